// Round 1
// baseline (1594.696 us; speedup 1.0000x reference)
//
#include <hip/hip_runtime.h>
#include <math.h>

#define BB 64
#define TT 2048
#define ADIM 384
#define NE 10    // num_embeddings == LSTM hidden
#define NG 40    // 4*NE gates
#define HD 3     // hidden_dim (codebook width)

// ---------------- workspace layout (bytes) ----------------
// X64   : BB*TT*NG*8   = 41,943,040
// W64T  : ADIM*NG*8    =    122,880   (W_ih transposed to [a][k], f64)
// Etab  : NE*NG*8      =      3,200   (codebook @ (W_ih@qs_W).T + qs_b@W_ih.T)
// h_ws  : BB*TT*NE*4   =  5,242,880   (f32 h history for deferred loss)
// idx_ws: BB*TT*4      =    524,288   (argmax indices for deferred gather)
// part  : 512*8        =      4,096
#define OFF_X64   0ULL
#define OFF_W64T  41943040ULL
#define OFF_ETAB  (OFF_W64T + 122880ULL)
#define OFF_H     (OFF_ETAB + 3200ULL)
#define OFF_IDX   (OFF_H + 5242880ULL)
#define OFF_PART  (OFF_IDX + 524288ULL)

// ---------------- setup: transpose W_ih to f64, build Etab ----------------
__global__ __launch_bounds__(256) void setup_kernel(
        const float* __restrict__ W_ih, const float* __restrict__ codebook,
        const float* __restrict__ qs_W, const float* __restrict__ qs_b,
        double* __restrict__ W64T, double* __restrict__ Etab) {
    int tid = threadIdx.x;
    for (int i = tid; i < ADIM * NG; i += 256) {
        int a = i / NG, k = i % NG;
        W64T[i] = (double)W_ih[k * ADIM + a];
    }
    if (tid < NG) {
        int k = tid;
        double M0 = 0, M1 = 0, M2 = 0, qb = 0;
        for (int a = 0; a < ADIM; ++a) {
            double w = (double)W_ih[k * ADIM + a];
            M0 = fma(w, (double)qs_W[a * HD + 0], M0);
            M1 = fma(w, (double)qs_W[a * HD + 1], M1);
            M2 = fma(w, (double)qs_W[a * HD + 2], M2);
            qb = fma(w, (double)qs_b[a], qb);
        }
        for (int i = 0; i < NE; ++i) {
            double e = qb;
            e = fma((double)codebook[i * HD + 0], M0, e);
            e = fma((double)codebook[i * HD + 1], M1, e);
            e = fma((double)codebook[i * HD + 2], M2, e);
            Etab[i * NG + k] = e;
        }
    }
}

// ---------------- X = hs @ W_ih.T  (f64 accumulate) ----------------
// block = 256 thr = 4 waves; each wave: 64 rows (one per lane) x 10 cols.
__global__ __launch_bounds__(256) void gemm_kernel(
        const float* __restrict__ hs, const double* __restrict__ W64T,
        double* __restrict__ X64) {
    int lane = threadIdx.x & 63;
    int wv = threadIdx.x >> 6;
    int cb = __builtin_amdgcn_readfirstlane(wv * 10);   // wave-uniform col base
    long row = (long)blockIdx.x * 64 + lane;            // < 131072
    const float* xr = hs + row * ADIM;
    double acc[10];
#pragma unroll
    for (int j = 0; j < 10; ++j) acc[j] = 0.0;
    for (int a0 = 0; a0 < ADIM; a0 += 4) {
        float4 xv = *(const float4*)(xr + a0);
#pragma unroll
        for (int u = 0; u < 4; ++u) {
            double xd = (double)((&xv.x)[u]);
            const double* wp = W64T + (a0 + u) * NG + cb;  // uniform addr -> broadcast
#pragma unroll
            for (int j = 0; j < 10; ++j) acc[j] = fma(wp[j], xd, acc[j]);
        }
    }
    double* op = X64 + row * NG + cb;
#pragma unroll
    for (int j = 0; j < 10; ++j) op[j] = acc[j];
}

// ---------------- sequential recurrence: one wave per batch ----------------
// lane k<40 owns gate k; lanes 0..9 own h/c; h broadcast via v_readlane (SGPR).
__global__ __launch_bounds__(64) void recur_kernel(
        const double* __restrict__ X64,
        const float* __restrict__ W_hh, const float* __restrict__ b_ih,
        const float* __restrict__ b_hh, const double* __restrict__ Etab,
        float* __restrict__ h_out, int* __restrict__ idx_out) {
    const int k = threadIdx.x;
    const int b = blockIdx.x;
    const int kc = (k < NG) ? k : NG - 1;   // clamp so idle lanes load safely

    double bias = (double)b_ih[kc] + (double)b_hh[kc];
    double whh[NE];
#pragma unroll
    for (int m = 0; m < NE; ++m) whh[m] = (double)W_hh[kc * NE + m];
    double etab[NE];
#pragma unroll
    for (int i = 0; i < NE; ++i) etab[i] = Etab[i * NG + kc];
    const bool isg = (k >= 20 && k < 30);   // g-gate lanes use tanh = 2*sig(2x)-1

    const double* Xb = X64 + (long)b * TT * NG;
    float* hob = h_out + (long)b * TT * NE;
    int* iob = idx_out + (long)b * TT;

    // prefetch ring depth 4
    double xs0 = Xb[0 * NG + kc];
    double xs1 = Xb[1 * NG + kc];
    double xs2 = Xb[2 * NG + kc];
    double xs3 = Xb[3 * NG + kc];

    double ha[NE];
#pragma unroll
    for (int m = 0; m < NE; ++m) ha[m] = 0.0;
    double c = 0.0, esel = 0.0;

    auto step = [&](double& xslot, int t) {
        double xg = xslot;
        int tp = t + 4; if (tp > TT - 1) tp = TT - 1;
        xslot = Xb[(long)tp * NG + kc];     // prefetch, consumed 4 steps later

        // gates[k] = X + bias + Etab[prev idx] + <h, W_hh[k,:]>   (balanced tree)
        double p0 = fma(ha[1], whh[1], ha[0] * whh[0]);
        double p1 = fma(ha[3], whh[3], ha[2] * whh[2]);
        double p2 = fma(ha[5], whh[5], ha[4] * whh[4]);
        double p3 = fma(ha[7], whh[7], ha[6] * whh[6]);
        double p4 = fma(ha[9], whh[9], ha[8] * whh[8]);
        double gate = ((xg + bias) + esel) + (((p0 + p1) + (p2 + p3)) + p4);

        // activation: sigmoid for i,f,o; tanh (=2*sig(2x)-1) for g — branchless
        double y = isg ? (gate + gate) : gate;
        double e = exp(-y);
        double sg = 1.0 / (1.0 + e);
        double act = isg ? (sg + sg - 1.0) : sg;

        // gather i,f,g,o onto lanes 0..9
        double iv = act;
        double fv = __shfl(act, k + 10);
        double gv = __shfl(act, k + 20);
        double ov = __shfl(act, k + 30);
        c = fma(fv, c, iv * gv);
        double e2 = exp(-(c + c));
        double th = (1.0 - e2) / (1.0 + e2);
        double h = ov * th;

        if (k < NE) hob[(long)t * NE + k] = (float)h;   // deferred loss input

        // argmax over lanes 0..9 (16-lane xor tree; ties -> lowest index)
        double av = (k < NE) ? h : -1.0e300;
        int ai = k;
#pragma unroll
        for (int off = 1; off < 16; off <<= 1) {
            double bv = __shfl_xor(av, off);
            int bi = __shfl_xor(ai, off);
            bool take = (bv > av) || (bv == av && bi < ai);
            av = take ? bv : av;
            ai = take ? bi : ai;
        }
        int idxb = __shfl(ai, 0);
        if (k == 0) iob[t] = idxb;

        // broadcast h into (uniform) SGPR-resident ha[]
#pragma unroll
        for (int m = 0; m < NE; ++m) {
            int lo = __builtin_amdgcn_readlane(__double2loint(h), m);
            int hi = __builtin_amdgcn_readlane(__double2hiint(h), m);
            ha[m] = __hiloint2double(hi, lo);
        }
        // Etab row select (uniform idx -> cndmask chain, no scratch)
        double es = etab[0];
#pragma unroll
        for (int i = 1; i < NE; ++i) es = (idxb == i) ? etab[i] : es;
        esel = es;
    };

    for (int t = 0; t < TT; t += 4) {
        step(xs0, t);
        step(xs1, t + 1);
        step(xs2, t + 2);
        step(xs3, t + 3);
    }
}

// ---------------- deferred: embs gather + NLL partial sums ----------------
__global__ __launch_bounds__(256) void tail_kernel(
        const float* __restrict__ h_ws, const int* __restrict__ idx_ws,
        const int* __restrict__ inds, const float* __restrict__ codebook,
        float* __restrict__ out_embs, double* __restrict__ partials) {
    int i = blockIdx.x * 256 + threadIdx.x;   // 512*256 == 131072 exactly
    int idx = idx_ws[i];
    out_embs[i * 3 + 0] = codebook[idx * 3 + 0];
    out_embs[i * 3 + 1] = codebook[idx * 3 + 1];
    out_embs[i * 3 + 2] = codebook[idx * 3 + 2];

    const float* hp = h_ws + (long)i * NE;
    double hv[NE];
#pragma unroll
    for (int m = 0; m < NE; ++m) hv[m] = (double)hp[m];
    double mx = hv[0];
#pragma unroll
    for (int m = 1; m < NE; ++m) mx = fmax(mx, hv[m]);
    double s = 0.0;
#pragma unroll
    for (int m = 0; m < NE; ++m) s += exp(hv[m] - mx);
    int ind = inds[i];
    double picked = (double)hp[ind] - (mx + log(s));

    __shared__ double red[256];
    red[threadIdx.x] = picked;
    __syncthreads();
    for (int st = 128; st > 0; st >>= 1) {
        if (threadIdx.x < st) red[threadIdx.x] += red[threadIdx.x + st];
        __syncthreads();
    }
    if (threadIdx.x == 0) partials[blockIdx.x] = red[0];
}

__global__ __launch_bounds__(256) void final_kernel(
        const double* __restrict__ partials, float* __restrict__ out_loss) {
    __shared__ double red[256];
    red[threadIdx.x] = partials[threadIdx.x] + partials[threadIdx.x + 256];
    __syncthreads();
    for (int st = 128; st > 0; st >>= 1) {
        if (threadIdx.x < st) red[threadIdx.x] += red[threadIdx.x + st];
        __syncthreads();
    }
    if (threadIdx.x == 0)
        out_loss[0] = (float)(-red[0] / (double)(BB * TT));
}

extern "C" void kernel_launch(void* const* d_in, const int* in_sizes, int n_in,
                              void* d_out, int out_size, void* d_ws, size_t ws_size,
                              hipStream_t stream) {
    const float* hs       = (const float*)d_in[0];
    const int*   inds     = (const int*)d_in[1];
    const float* codebook = (const float*)d_in[2];
    const float* W_ih     = (const float*)d_in[3];
    const float* W_hh     = (const float*)d_in[4];
    const float* b_ih     = (const float*)d_in[5];
    const float* b_hh     = (const float*)d_in[6];
    const float* qs_W     = (const float*)d_in[7];
    const float* qs_b     = (const float*)d_in[8];
    float* out = (float*)d_out;

    char* ws = (char*)d_ws;
    double* X64   = (double*)(ws + OFF_X64);
    double* W64T  = (double*)(ws + OFF_W64T);
    double* Etab  = (double*)(ws + OFF_ETAB);
    float*  h_ws  = (float*)(ws + OFF_H);
    int*    idx_ws= (int*)(ws + OFF_IDX);
    double* part  = (double*)(ws + OFF_PART);

    setup_kernel<<<1, 256, 0, stream>>>(W_ih, codebook, qs_W, qs_b, W64T, Etab);
    gemm_kernel<<<2048, 256, 0, stream>>>(hs, W64T, X64);
    recur_kernel<<<BB, 64, 0, stream>>>(X64, W_hh, b_ih, b_hh, Etab, h_ws, idx_ws);
    tail_kernel<<<512, 256, 0, stream>>>(h_ws, idx_ws, inds, codebook, out, part);
    final_kernel<<<1, 256, 0, stream>>>(part, out + (size_t)BB * TT * HD);
}

// Round 2
// 999.295 us; speedup vs baseline: 1.5958x; 1.5958x over previous
//
#include <hip/hip_runtime.h>
#include <math.h>

#define BB 64
#define TT 2048
#define ADIM 384
#define NE 10    // num_embeddings == LSTM hidden
#define NG 40    // 4*NE gates
#define HD 3     // hidden_dim (codebook width)

// ---------------- workspace layout (bytes) ----------------
#define OFF_X64   0ULL
#define OFF_W64T  41943040ULL
#define OFF_ETAB  (OFF_W64T + 122880ULL)
#define OFF_H     (OFF_ETAB + 3200ULL)
#define OFF_IDX   (OFF_H + 5242880ULL)
#define OFF_PART  (OFF_IDX + 524288ULL)

// ---------------- fast f64 math (latency-optimized, ~1e-16 rel err) -------
__device__ __forceinline__ double fast_exp(double x) {
    // e^x = 2^n * e^r ; n = rndne(x*log2e) via magic-add (also yields int n)
    const double LOG2E = 1.4426950408889634074;
    const double LN2HI = 6.93147180369123816490e-01;  // low 32 bits zero
    const double LN2LO = 1.90821492927058770002e-10;
    const double MAGIC = 6755399441055744.0;          // 1.5*2^52
    double t  = x * LOG2E;
    double sh = t + MAGIC;
    double n  = sh - MAGIC;
    int    ni = __double2loint(sh);     // two's-complement integer n
    double r  = fma(-n, LN2HI, x);
    r = fma(-n, LN2LO, r);
    // e^r, |r| <= 0.3466, Taylor deg 12, Estrin (depth ~5 FMA)
    double r2 = r * r, r4 = r2 * r2, r8 = r4 * r4;
    double T1 = fma(r2, fma(r, 1.0/6.0, 0.5), r + 1.0);
    double T2 = fma(r2, fma(r, 1.0/5040.0, 1.0/720.0), fma(r, 1.0/120.0, 1.0/24.0));
    double T3 = fma(r2, fma(r, 1.0/39916800.0, 1.0/3628800.0),
                    fma(r, 1.0/362880.0, 1.0/40320.0));
    T3 = fma(r4, 1.0/479001600.0, T3);
    double P = fma(r8, T3, fma(r4, T2, T1));
    return ldexp(P, ni);                // v_ldexp_f64 (handles under/overflow)
}

__device__ __forceinline__ double fast_rcp(double d) {
    double r = __builtin_amdgcn_rcp(d);    // v_rcp_f64 seed
    double e = fma(-d, r, 1.0);
    r = fma(r, e, r);
    e = fma(-d, r, 1.0);
    r = fma(r, e, r);                       // err ~2^-56
    return r;
}

template<int CTRL, int RMASK>
__device__ __forceinline__ double dpp_mov_f64(double x) {
    int lo = __double2loint(x), hi = __double2hiint(x);
    lo = __builtin_amdgcn_update_dpp(lo, lo, CTRL, RMASK, 0xF, true);
    hi = __builtin_amdgcn_update_dpp(hi, hi, CTRL, RMASK, 0xF, true);
    return __hiloint2double(hi, lo);
}

// ---------------- setup: transpose W_ih to f64, build Etab ----------------
__global__ __launch_bounds__(256) void setup_kernel(
        const float* __restrict__ W_ih, const float* __restrict__ codebook,
        const float* __restrict__ qs_W, const float* __restrict__ qs_b,
        double* __restrict__ W64T, double* __restrict__ Etab) {
    int tid = threadIdx.x;
    for (int i = tid; i < ADIM * NG; i += 256) {
        int a = i / NG, k = i % NG;
        W64T[i] = (double)W_ih[k * ADIM + a];
    }
    if (tid < NG) {
        int k = tid;
        double M0 = 0, M1 = 0, M2 = 0, qb = 0;
        for (int a = 0; a < ADIM; ++a) {
            double w = (double)W_ih[k * ADIM + a];
            M0 = fma(w, (double)qs_W[a * HD + 0], M0);
            M1 = fma(w, (double)qs_W[a * HD + 1], M1);
            M2 = fma(w, (double)qs_W[a * HD + 2], M2);
            qb = fma(w, (double)qs_b[a], qb);
        }
        for (int i = 0; i < NE; ++i) {
            double e = qb;
            e = fma((double)codebook[i * HD + 0], M0, e);
            e = fma((double)codebook[i * HD + 1], M1, e);
            e = fma((double)codebook[i * HD + 2], M2, e);
            Etab[i * NG + k] = e;
        }
    }
}

// ---------------- X = hs @ W_ih.T  (f64 accumulate) ----------------
__global__ __launch_bounds__(256) void gemm_kernel(
        const float* __restrict__ hs, const double* __restrict__ W64T,
        double* __restrict__ X64) {
    int lane = threadIdx.x & 63;
    int wv = threadIdx.x >> 6;
    int cb = __builtin_amdgcn_readfirstlane(wv * 10);   // wave-uniform col base
    long row = (long)blockIdx.x * 64 + lane;            // < 131072
    const float* xr = hs + row * ADIM;
    double acc[10];
#pragma unroll
    for (int j = 0; j < 10; ++j) acc[j] = 0.0;
    for (int a0 = 0; a0 < ADIM; a0 += 4) {
        float4 xv = *(const float4*)(xr + a0);
#pragma unroll
        for (int u = 0; u < 4; ++u) {
            double xd = (double)((&xv.x)[u]);
            const double* wp = W64T + (a0 + u) * NG + cb;  // uniform -> broadcast
#pragma unroll
            for (int j = 0; j < 10; ++j) acc[j] = fma(wp[j], xd, acc[j]);
        }
    }
    double* op = X64 + row * NG + cb;
#pragma unroll
    for (int j = 0; j < 10; ++j) op[j] = acc[j];
}

// ---------------- sequential recurrence: one wave per batch ----------------
// QUAD layout: lane 4m+j holds gate type j (i,f,g,o) of embedding m (m<10).
// No LDS/bpermute on the critical path: quad_perm DPP gather, DPP argmax.
__global__ __launch_bounds__(64) void recur_kernel(
        const double* __restrict__ X64,
        const float* __restrict__ W_hh, const float* __restrict__ b_ih,
        const float* __restrict__ b_hh, const double* __restrict__ Etab,
        float* __restrict__ h_out, int* __restrict__ idx_out) {
    const int k = threadIdx.x;
    const int b = blockIdx.x;
    const int j = k & 3;                 // gate type 0..3 = i,f,g,o
    const int m = k >> 2;                // embedding index (valid < 10)
    const bool valid = (k < NG);
    const int col = valid ? (j * 10 + m) : (NG - 1);  // row in W_ih/W_hh order
    const bool isg = (j == 2);           // g-gate -> tanh = 2*sig(2x)-1

    double bias = (double)b_ih[col] + (double)b_hh[col];
    double whh[NE];
#pragma unroll
    for (int mm = 0; mm < NE; ++mm) whh[mm] = (double)W_hh[col * NE + mm];
    double etab[NE];
#pragma unroll
    for (int i = 0; i < NE; ++i) etab[i] = Etab[i * NG + col];

    const double* Xb = X64 + (long)b * TT * NG;
    float* hob = h_out + (long)b * TT * NE;
    int* iob = idx_out + (long)b * TT;

    // prefetch ring depth 4
    double xs0 = Xb[0 * NG + col];
    double xs1 = Xb[1 * NG + col];
    double xs2 = Xb[2 * NG + col];
    double xs3 = Xb[3 * NG + col];

    double ha[NE];
#pragma unroll
    for (int mm = 0; mm < NE; ++mm) ha[mm] = 0.0;
    double c = 0.0, esel = 0.0;

    auto step = [&](double& xslot, int t) {
        double xg = xslot;
        int tp = t + 4; if (tp > TT - 1) tp = TT - 1;
        xslot = Xb[(long)tp * NG + col];     // prefetch, consumed 4 steps later

        // gate = X + bias + Etab[prev idx] + <h_prev, W_hh[col,:]>
        double p0 = fma(ha[1], whh[1], ha[0] * whh[0]);
        double p1 = fma(ha[3], whh[3], ha[2] * whh[2]);
        double p2 = fma(ha[5], whh[5], ha[4] * whh[4]);
        double p3 = fma(ha[7], whh[7], ha[6] * whh[6]);
        double p4 = fma(ha[9], whh[9], ha[8] * whh[8]);
        double gate = ((xg + bias) + esel) + (((p0 + p1) + (p2 + p3)) + p4);

        // activation: sigmoid (i,f,o) / tanh (g) — branchless
        double y = isg ? (gate + gate) : gate;
        double e = fast_exp(-y);
        double s = fast_rcp(1.0 + e);
        double act = isg ? (s + s - 1.0) : s;

        // in-quad gather via quad_perm DPP (each lane gets its quad's i,f,g,o)
        double fi = dpp_mov_f64<0x00, 0xF>(act);
        double ff = dpp_mov_f64<0x55, 0xF>(act);
        double fg = dpp_mov_f64<0xAA, 0xF>(act);
        double fo = dpp_mov_f64<0xFF, 0xF>(act);

        c = fma(ff, c, fi * fg);             // redundant per quad
        double acb = fabs(c);
        double e2 = fast_exp(-(acb + acb));  // in (0,1] -> NR-safe denom
        double th = (1.0 - e2) * fast_rcp(1.0 + e2);
        th = copysign(th, c);
        double h = fo * th;                  // h_m on all 4 lanes of quad m

        // argmax over m: pack (15-m) into low 4 mantissa bits, DPP max-reduce.
        // quad redundancy => ror4+ror8 reduce each row, bcast15/31 -> lane32.
        double key;
        {
            long long kb = __double_as_longlong(h);
            kb = (kb & ~0xFLL) | (long long)(15 - m);
            key = __longlong_as_double(kb);
            if (!valid) key = -1.0e300;
        }
        key = fmax(key, dpp_mov_f64<0x124, 0xF>(key));  // row_ror:4
        key = fmax(key, dpp_mov_f64<0x128, 0xF>(key));  // row_ror:8
        key = fmax(key, dpp_mov_f64<0x142, 0xA>(key));  // bcast15 -> row1(,3)
        key = fmax(key, dpp_mov_f64<0x143, 0xC>(key));  // bcast31 -> rows2,3
        int slo = __builtin_amdgcn_readlane(__double2loint(key), 32);
        int s_idx = 15 - (slo & 15);         // wave-uniform argmax index

        // store h (lanes 4m) and idx (lane 40) in one masked store
        if ((k & 3) == 0 && k <= NG) {
            int val = valid ? __float_as_int((float)h) : s_idx;
            int* ap = valid ? ((int*)hob + (long)t * NE + m) : (iob + t);
            *ap = val;
        }

        // broadcast h into SGPR-resident ha[] (one quad-lane per embedding)
#pragma unroll
        for (int mm = 0; mm < NE; ++mm) {
            int lo = __builtin_amdgcn_readlane(__double2loint(h), 4 * mm);
            int hi = __builtin_amdgcn_readlane(__double2hiint(h), 4 * mm);
            ha[mm] = __hiloint2double(hi, lo);
        }
        // Etab row select: scalar-compare cndmask chain (|| with dot path)
        double es = etab[0];
#pragma unroll
        for (int i = 1; i < NE; ++i) es = (s_idx == i) ? etab[i] : es;
        esel = es;
    };

    for (int t = 0; t < TT; t += 4) {
        step(xs0, t);
        step(xs1, t + 1);
        step(xs2, t + 2);
        step(xs3, t + 3);
    }
}

// ---------------- deferred: embs gather + NLL partial sums ----------------
__global__ __launch_bounds__(256) void tail_kernel(
        const float* __restrict__ h_ws, const int* __restrict__ idx_ws,
        const int* __restrict__ inds, const float* __restrict__ codebook,
        float* __restrict__ out_embs, double* __restrict__ partials) {
    int i = blockIdx.x * 256 + threadIdx.x;   // 512*256 == 131072 exactly
    int idx = idx_ws[i];
    out_embs[i * 3 + 0] = codebook[idx * 3 + 0];
    out_embs[i * 3 + 1] = codebook[idx * 3 + 1];
    out_embs[i * 3 + 2] = codebook[idx * 3 + 2];

    const float* hp = h_ws + (long)i * NE;
    double hv[NE];
#pragma unroll
    for (int mm = 0; mm < NE; ++mm) hv[mm] = (double)hp[mm];
    double mx = hv[0];
#pragma unroll
    for (int mm = 1; mm < NE; ++mm) mx = fmax(mx, hv[mm]);
    double sdn = 0.0;
#pragma unroll
    for (int mm = 0; mm < NE; ++mm) sdn += exp(hv[mm] - mx);
    int ind = inds[i];
    double picked = (double)hp[ind] - (mx + log(sdn));

    __shared__ double red[256];
    red[threadIdx.x] = picked;
    __syncthreads();
    for (int st = 128; st > 0; st >>= 1) {
        if (threadIdx.x < st) red[threadIdx.x] += red[threadIdx.x + st];
        __syncthreads();
    }
    if (threadIdx.x == 0) partials[blockIdx.x] = red[0];
}

__global__ __launch_bounds__(256) void final_kernel(
        const double* __restrict__ partials, float* __restrict__ out_loss) {
    __shared__ double red[256];
    red[threadIdx.x] = partials[threadIdx.x] + partials[threadIdx.x + 256];
    __syncthreads();
    for (int st = 128; st > 0; st >>= 1) {
        if (threadIdx.x < st) red[threadIdx.x] += red[threadIdx.x + st];
        __syncthreads();
    }
    if (threadIdx.x == 0)
        out_loss[0] = (float)(-red[0] / (double)(BB * TT));
}

extern "C" void kernel_launch(void* const* d_in, const int* in_sizes, int n_in,
                              void* d_out, int out_size, void* d_ws, size_t ws_size,
                              hipStream_t stream) {
    const float* hs       = (const float*)d_in[0];
    const int*   inds     = (const int*)d_in[1];
    const float* codebook = (const float*)d_in[2];
    const float* W_ih     = (const float*)d_in[3];
    const float* W_hh     = (const float*)d_in[4];
    const float* b_ih     = (const float*)d_in[5];
    const float* b_hh     = (const float*)d_in[6];
    const float* qs_W     = (const float*)d_in[7];
    const float* qs_b     = (const float*)d_in[8];
    float* out = (float*)d_out;

    char* ws = (char*)d_ws;
    double* X64   = (double*)(ws + OFF_X64);
    double* W64T  = (double*)(ws + OFF_W64T);
    double* Etab  = (double*)(ws + OFF_ETAB);
    float*  h_ws  = (float*)(ws + OFF_H);
    int*    idx_ws= (int*)(ws + OFF_IDX);
    double* part  = (double*)(ws + OFF_PART);

    setup_kernel<<<1, 256, 0, stream>>>(W_ih, codebook, qs_W, qs_b, W64T, Etab);
    gemm_kernel<<<2048, 256, 0, stream>>>(hs, W64T, X64);
    recur_kernel<<<BB, 64, 0, stream>>>(X64, W_hh, b_ih, b_hh, Etab, h_ws, idx_ws);
    tail_kernel<<<512, 256, 0, stream>>>(h_ws, idx_ws, inds, codebook, out, part);
    final_kernel<<<1, 256, 0, stream>>>(part, out + (size_t)BB * TT * HD);
}

// Round 4
// 959.138 us; speedup vs baseline: 1.6626x; 1.0419x over previous
//
#include <hip/hip_runtime.h>
#include <math.h>

#define BB 64
#define TT 2048
#define ADIM 384
#define NE 10    // num_embeddings == LSTM hidden
#define NG 40    // 4*NE gates
#define HD 3     // hidden_dim (codebook width)

// ---------------- workspace layout (bytes) ----------------
#define OFF_X64   0ULL
#define OFF_W64T  41943040ULL
#define OFF_ETAB  (OFF_W64T + 122880ULL)
#define OFF_H     (OFF_ETAB + 3200ULL)
#define OFF_IDX   (OFF_H + 5242880ULL)
#define OFF_PART  (OFF_IDX + 524288ULL)

// ---------------- fast f64 math (latency-optimized) -------
// e^{v*xmul}; L = xmul*log2(e) precomputed per lane. ~7e-15 rel err.
__device__ __forceinline__ double expcore(double v, double L, double xmul) {
    const double LN2HI = 6.93147180369123816490e-01;  // low 32 bits zero
    const double LN2LO = 1.90821492927058770002e-10;
    const double MAGIC = 6755399441055744.0;          // 1.5*2^52
    double sh = fma(v, L, MAGIC);       // round(v*xmul*log2e) in low mantissa
    double x  = v * xmul;               // parallel with sh
    double n  = sh - MAGIC;
    int    ni = __double2loint(sh);     // two's-complement integer n
    double r  = fma(-n, LN2HI, x);
    r = fma(-n, LN2LO, r);
    double r2 = r * r;
    double r4 = r2 * r2;
    double T1 = fma(r2, fma(r, 1.0/6.0, 0.5), r + 1.0);
    double T2 = fma(r2, fma(r, 1.0/5040.0, 1.0/720.0),
                    fma(r, 1.0/120.0, 1.0/24.0));
    double T3 = fma(r2, fma(r, 1.0/39916800.0, 1.0/3628800.0),
                    fma(r, 1.0/362880.0, 1.0/40320.0));
    double r8 = r4 * r4;
    double P = fma(r8, T3, fma(r4, T2, T1));
    return ldexp(P, ni);
}

__device__ __forceinline__ double rcp1(double d) {   // 1 NR: err ~2^-54
    double r = __builtin_amdgcn_rcp(d);
    double e = fma(-d, r, 1.0);
    return fma(r, e, r);
}

template<int CTRL, int RMASK>
__device__ __forceinline__ double dpp_mov_f64(double x) {
    int lo = __double2loint(x), hi = __double2hiint(x);
    lo = __builtin_amdgcn_update_dpp(lo, lo, CTRL, RMASK, 0xF, true);
    hi = __builtin_amdgcn_update_dpp(hi, hi, CTRL, RMASK, 0xF, true);
    return __hiloint2double(hi, lo);
}

// ---------------- setup: transpose W_ih to f64, build Etab ----------------
__global__ __launch_bounds__(256) void setup_kernel(
        const float* __restrict__ W_ih, const float* __restrict__ codebook,
        const float* __restrict__ qs_W, const float* __restrict__ qs_b,
        double* __restrict__ W64T, double* __restrict__ Etab) {
    int tid = threadIdx.x;
    if (blockIdx.x == 0) {
        if (tid < NG) {
            int k = tid;
            double M0 = 0, M1 = 0, M2 = 0, qb = 0;
            for (int a = 0; a < ADIM; ++a) {
                double w = (double)W_ih[k * ADIM + a];
                M0 = fma(w, (double)qs_W[a * HD + 0], M0);
                M1 = fma(w, (double)qs_W[a * HD + 1], M1);
                M2 = fma(w, (double)qs_W[a * HD + 2], M2);
                qb = fma(w, (double)qs_b[a], qb);
            }
            for (int i = 0; i < NE; ++i) {
                double e = qb;
                e = fma((double)codebook[i * HD + 0], M0, e);
                e = fma((double)codebook[i * HD + 1], M1, e);
                e = fma((double)codebook[i * HD + 2], M2, e);
                Etab[i * NG + k] = e;
            }
        }
    } else {
        int i = (blockIdx.x - 1) * 256 + tid;
        if (i < ADIM * NG) {
            int a = i / NG, k = i % NG;
            W64T[i] = (double)W_ih[k * ADIM + a];
        }
    }
}

// ---------------- X = hs @ W_ih.T  (f64 accumulate) ----------------
__global__ __launch_bounds__(256) void gemm_kernel(
        const float* __restrict__ hs, const double* __restrict__ W64T,
        double* __restrict__ X64) {
    int lane = threadIdx.x & 63;
    int wv = threadIdx.x >> 6;
    int cb = __builtin_amdgcn_readfirstlane(wv * 10);   // wave-uniform col base
    long row = (long)blockIdx.x * 64 + lane;            // < 131072
    const float* xr = hs + row * ADIM;
    double acc[10];
#pragma unroll
    for (int j = 0; j < 10; ++j) acc[j] = 0.0;
    for (int a0 = 0; a0 < ADIM; a0 += 4) {
        float4 xv = *(const float4*)(xr + a0);
#pragma unroll
        for (int u = 0; u < 4; ++u) {
            double xd = (double)((&xv.x)[u]);
            const double* wp = W64T + (a0 + u) * NG + cb;  // uniform -> broadcast
#pragma unroll
            for (int j = 0; j < 10; ++j) acc[j] = fma(wp[j], xd, acc[j]);
        }
    }
    double* op = X64 + row * NG + cb;
#pragma unroll
    for (int j = 0; j < 10; ++j) op[j] = acc[j];
}

// ---------------- sequential recurrence: one wave per batch ----------------
// QUAD layout: lane 4m+j holds gate type j (i,f,g,o) of embedding m (m<10).
// All 4 lanes of quad m compute IDENTICAL c,h (quad-redundant) — the DPP
// argmax rotation reduce REQUIRES this redundancy. Do not remove the i-gate
// broadcast: it costs nothing (parallel with f/g/o broadcasts) and without
// it lanes j!=0 hold garbage keys that corrupt the argmax (R3 bug).
__global__ __launch_bounds__(64) void recur_kernel(
        const double* __restrict__ X64,
        const float* __restrict__ W_hh, const float* __restrict__ b_ih,
        const float* __restrict__ b_hh, const double* __restrict__ Etab,
        float* __restrict__ h_out, int* __restrict__ idx_out) {
    const int k = threadIdx.x;
    const int b = blockIdx.x;
    const int j = k & 3;                 // gate type 0..3 = i,f,g,o
    const int m = k >> 2;                // embedding index (valid < 10)
    const bool valid = (k < NG);
    const int col = valid ? (j * 10 + m) : (NG - 1);  // row in W_ih/W_hh order
    const bool isg = (j == 2);           // g-gate -> tanh

    const double LOG2E = 1.4426950408889634074;
    const double Lc = isg ? (-2.0 * LOG2E) : (-LOG2E);  // fold sign+2x into exp
    const double xc = isg ? -2.0 : -1.0;
    const double LT = -2.0 * LOG2E;                      // tanh-side constants

    double bias = (double)b_ih[col] + (double)b_hh[col];
    double whh[NE];
#pragma unroll
    for (int mm = 0; mm < NE; ++mm) whh[mm] = (double)W_hh[col * NE + mm];
    double etab[NE];
#pragma unroll
    for (int i = 0; i < NE; ++i) etab[i] = Etab[i * NG + col];

    const double* Xb = X64 + (long)b * TT * NG;
    float* hob = h_out + (long)b * TT * NE;
    int* iob = idx_out + (long)b * TT;

    // prefetch ring depth 4
    double xs0 = Xb[0 * NG + col];
    double xs1 = Xb[1 * NG + col];
    double xs2 = Xb[2 * NG + col];
    double xs3 = Xb[3 * NG + col];

    double ha[NE];
#pragma unroll
    for (int mm = 0; mm < NE; ++mm) ha[mm] = 0.0;
    double c = 0.0, esel = 0.0;

    auto step = [&](double& xslot, int t) {
        double xg = xslot;
        int tp = t + 4; if (tp > TT - 1) tp = TT - 1;
        xslot = Xb[(long)tp * NG + col];     // prefetch, consumed 4 steps later

        // gate = (X + bias + esel) + <h_prev, W_hh[col,:]>
        double p0 = fma(ha[1], whh[1], ha[0] * whh[0]);
        double p1 = fma(ha[3], whh[3], ha[2] * whh[2]);
        double p2 = fma(ha[5], whh[5], ha[4] * whh[4]);
        double p3 = fma(ha[7], whh[7], ha[6] * whh[6]);
        double p4 = fma(ha[9], whh[9], ha[8] * whh[8]);
        double dot = ((p0 + p1) + (p2 + p3)) + p4;
        double gate = ((xg + bias) + esel) + dot;

        // sigmoid (i,f,o) / tanh (g) via one exp + one rcp:
        //   e = e^{xc*gate};  act = num * rcp(1+e);  num = isg ? 1-e : 1
        double e1 = expcore(gate, Lc, xc);
        double d1 = 1.0 + e1;
        double r1 = rcp1(d1);
        double num = isg ? (1.0 - e1) : 1.0;
        double act = num * r1;

        // quad gather: broadcast ALL FOUR gates so every lane of the quad
        // computes the same c,h (required by the argmax reduce below).
        double fiv = dpp_mov_f64<0x00, 0xF>(act);
        double ffv = dpp_mov_f64<0x55, 0xF>(act);
        double fgv = dpp_mov_f64<0xAA, 0xF>(act);
        double fov = dpp_mov_f64<0xFF, 0xF>(act);
        c = fma(ffv, c, fiv * fgv);          // identical across quad

        double acb = fabs(c);
        double e2 = expcore(acb, LT, -2.0);  // e^{-2|c|} in (0,1] -> NR-safe
        double d2 = 1.0 + e2;
        double q2 = 1.0 - e2;
        double r2 = rcp1(d2);
        double h = copysign((q2 * fov) * r2, c);   // identical across quad

        // argmax over m: pack (15-m) into low 4 mantissa bits, DPP max-reduce
        // (quad redundancy => ror4+ror8 reduce each 16-lane row, then
        //  bcast15/bcast31 push the global max into row 2; read lane 32)
        int hlo = __double2loint(h), hhi = __double2hiint(h);
        int klo = (hlo & ~15) | (15 - m);
        double key = __hiloint2double(hhi, klo);
        key = valid ? key : -1.0e300;
        key = fmax(key, dpp_mov_f64<0x124, 0xF>(key));  // row_ror:4
        key = fmax(key, dpp_mov_f64<0x128, 0xF>(key));  // row_ror:8
        key = fmax(key, dpp_mov_f64<0x142, 0xA>(key));  // bcast15 -> row1
        key = fmax(key, dpp_mov_f64<0x143, 0xC>(key));  // bcast31 -> rows2,3
        int slo = __builtin_amdgcn_readlane(__double2loint(key), 32);
        int s_idx = 15 - (slo & 15);         // wave-uniform argmax index

        // store h (lanes 4m, m<10) and idx (lane 40) in one masked store
        if ((k & 3) == 0 && k <= NG) {
            int val = valid ? __float_as_int((float)h) : s_idx;
            int* ap = valid ? ((int*)hob + (long)t * NE + m) : (iob + t);
            *ap = val;
        }

        // broadcast h into SGPR-resident ha[] (quad-lane 4m per embedding)
#pragma unroll
        for (int mm = 0; mm < NE; ++mm) {
            int lo = __builtin_amdgcn_readlane(hlo, 4 * mm);
            int hi = __builtin_amdgcn_readlane(hhi, 4 * mm);
            ha[mm] = __hiloint2double(hi, lo);
        }
        // esel = etab[s_idx]: 4-level bit-tree select (depth 4, not 9)
        double a0 = (s_idx & 1) ? etab[1] : etab[0];
        double a1 = (s_idx & 1) ? etab[3] : etab[2];
        double a2 = (s_idx & 1) ? etab[5] : etab[4];
        double a3 = (s_idx & 1) ? etab[7] : etab[6];
        double a4 = (s_idx & 1) ? etab[9] : etab[8];
        double b0 = (s_idx & 2) ? a1 : a0;
        double b1 = (s_idx & 2) ? a3 : a2;
        double c0 = (s_idx & 4) ? b1 : b0;
        esel = (s_idx & 8) ? a4 : c0;
    };

    for (int t = 0; t < TT; t += 4) {
        step(xs0, t);
        step(xs1, t + 1);
        step(xs2, t + 2);
        step(xs3, t + 3);
    }
}

// ---------------- deferred: embs gather + NLL partial sums ----------------
__global__ __launch_bounds__(256) void tail_kernel(
        const float* __restrict__ h_ws, const int* __restrict__ idx_ws,
        const int* __restrict__ inds, const float* __restrict__ codebook,
        float* __restrict__ out_embs, double* __restrict__ partials) {
    int i = blockIdx.x * 256 + threadIdx.x;   // 512*256 == 131072 exactly
    int idx = idx_ws[i];
    out_embs[i * 3 + 0] = codebook[idx * 3 + 0];
    out_embs[i * 3 + 1] = codebook[idx * 3 + 1];
    out_embs[i * 3 + 2] = codebook[idx * 3 + 2];

    const float* hp = h_ws + (long)i * NE;
    double hv[NE];
#pragma unroll
    for (int mm = 0; mm < NE; ++mm) hv[mm] = (double)hp[mm];
    double mx = hv[0];
#pragma unroll
    for (int mm = 1; mm < NE; ++mm) mx = fmax(mx, hv[mm]);
    double sdn = 0.0;
#pragma unroll
    for (int mm = 0; mm < NE; ++mm) sdn += exp(hv[mm] - mx);
    int ind = inds[i];
    double picked = (double)hp[ind] - (mx + log(sdn));

    __shared__ double red[256];
    red[threadIdx.x] = picked;
    __syncthreads();
    for (int st = 128; st > 0; st >>= 1) {
        if (threadIdx.x < st) red[threadIdx.x] += red[threadIdx.x + st];
        __syncthreads();
    }
    if (threadIdx.x == 0) partials[blockIdx.x] = red[0];
}

__global__ __launch_bounds__(256) void final_kernel(
        const double* __restrict__ partials, float* __restrict__ out_loss) {
    __shared__ double red[256];
    red[threadIdx.x] = partials[threadIdx.x] + partials[threadIdx.x + 256];
    __syncthreads();
    for (int st = 128; st > 0; st >>= 1) {
        if (threadIdx.x < st) red[threadIdx.x] += red[threadIdx.x + st];
        __syncthreads();
    }
    if (threadIdx.x == 0)
        out_loss[0] = (float)(-red[0] / (double)(BB * TT));
}

extern "C" void kernel_launch(void* const* d_in, const int* in_sizes, int n_in,
                              void* d_out, int out_size, void* d_ws, size_t ws_size,
                              hipStream_t stream) {
    const float* hs       = (const float*)d_in[0];
    const int*   inds     = (const int*)d_in[1];
    const float* codebook = (const float*)d_in[2];
    const float* W_ih     = (const float*)d_in[3];
    const float* W_hh     = (const float*)d_in[4];
    const float* b_ih     = (const float*)d_in[5];
    const float* b_hh     = (const float*)d_in[6];
    const float* qs_W     = (const float*)d_in[7];
    const float* qs_b     = (const float*)d_in[8];
    float* out = (float*)d_out;

    char* ws = (char*)d_ws;
    double* X64   = (double*)(ws + OFF_X64);
    double* W64T  = (double*)(ws + OFF_W64T);
    double* Etab  = (double*)(ws + OFF_ETAB);
    float*  h_ws  = (float*)(ws + OFF_H);
    int*    idx_ws= (int*)(ws + OFF_IDX);
    double* part  = (double*)(ws + OFF_PART);

    setup_kernel<<<61, 256, 0, stream>>>(W_ih, codebook, qs_W, qs_b, W64T, Etab);
    gemm_kernel<<<2048, 256, 0, stream>>>(hs, W64T, X64);
    recur_kernel<<<BB, 64, 0, stream>>>(X64, W_hh, b_ih, b_hh, Etab, h_ws, idx_ws);
    tail_kernel<<<512, 256, 0, stream>>>(h_ws, idx_ws, inds, codebook, out, part);
    final_kernel<<<1, 256, 0, stream>>>(part, out + (size_t)BB * TT * HD);
}